// Round 11
// baseline (322.565 us; speedup 1.0000x reference)
//
#include <hip/hip_runtime.h>
#include <cstdint>
#include <cstddef>

#define DI static __device__ __forceinline__

using half_t  = _Float16;
using half2_t = __attribute__((ext_vector_type(2))) _Float16;
using half8_t = __attribute__((ext_vector_type(8))) _Float16;
using f32x4_t = __attribute__((ext_vector_type(4))) float;

DI uint32_t pack2(float a, float b){ half2_t h; h[0]=(half_t)a; h[1]=(half_t)b; return __builtin_bit_cast(uint32_t,h); }
DI uint16_t f16b(float a){ return __builtin_bit_cast(uint16_t,(half_t)a); }
DI float lo16(uint32_t u){ half2_t h=__builtin_bit_cast(half2_t,u); return (float)h[0]; }
DI float hi16(uint32_t u){ half2_t h=__builtin_bit_cast(half2_t,u); return (float)h[1]; }
DI float fdot2(uint32_t w, uint32_t x, float acc){
  return __builtin_amdgcn_fdot2(__builtin_bit_cast(half2_t,w), __builtin_bit_cast(half2_t,x), acc, false);
}
DI float sigm(float x){ return __builtin_amdgcn_rcpf(1.f + __expf(-x)); }
DI float tanhf_(float x){ return 1.f - 2.f*__builtin_amdgcn_rcpf(__expf(2.f*x)+1.f); }

// problem sizes: B=32 S=64 NW=2048 T=198 L=50 WLEN=20 BERT=178 Hs=128 Hm=256 Din=306 O=32
#define SROW 308   // sentences_in row stride (306 used)
#define HSTR 280   // k_srec h-row stride in halves
#define ASTR 344   // k_sxg A-row stride in halves

// prep-role job sizes (sentence weights only; word weights self-packed in word role)
#define P4 262144  // sent Whh B-frag layout [dir][ng1024][kp128], ng = w*128 + g*32 + jl
#define P5 327680  // sent Wih B-frag layout [dir][ng1024][kp160] (306 -> kp<153, rest 0)
#define P6 2048    // sent bias sum [dir][j256][g4]
#define P7 8192    // Wo f16x2 [kp256][o32]
#define PTOT (P4+P5+P6+P7)

// ---- fused kernel: blocks 0..127 = word LSTM (MFMA, self-packed weights);
//      blocks 128..511 = sentence-weight prep (grid-stride).
//      IDEMPOTENT: launched twice this round to measure its duration via the total.
__global__ __launch_bounds__(512, 2) void k_wp(
    const float* __restrict__ X, const float* __restrict__ h0w, const float* __restrict__ c0w,
    const float* __restrict__ Wih_w, const float* __restrict__ Whh_w,
    const float* __restrict__ bih_w, const float* __restrict__ bhh_w,
    const float* __restrict__ Wl, const float* __restrict__ bl,
    const float* __restrict__ Wih_f, const float* __restrict__ Whh_f,
    const float* __restrict__ Wih_b, const float* __restrict__ Whh_b,
    const float* __restrict__ bih_f, const float* __restrict__ bhh_f,
    const float* __restrict__ bih_b, const float* __restrict__ bhh_b,
    const float* __restrict__ Wo,
    uint32_t* __restrict__ wWs, uint32_t* __restrict__ wWihs,
    float* __restrict__ wbss, uint32_t* __restrict__ wWo,
    float* __restrict__ sent)
{
  if (blockIdx.x >= 128) {
    // ---------------- prep role ----------------
    for (int i = (blockIdx.x - 128)*blockDim.x + threadIdx.x; i < PTOT;
         i += (gridDim.x - 128)*blockDim.x) {
      int id = i;
      if (id < P4) {                     // sent Whh B-frags
        int kp = id & 127, ng = (id>>7)&1023, dir = id>>17;
        int w = ng>>7, g = (ng>>5)&3, jl = ng&31;
        int row = g*256 + w*32 + jl;
        const float* s = (dir ? Whh_b : Whh_f) + (size_t)row*256 + 2*kp;
        wWs[id] = pack2(s[0], s[1]);
      } else if ((id -= P4) < P5) {      // sent Wih B-frags [dir][ng1024][kp160]
        int kp = id % 160; int q = id / 160;
        int ng = q & 1023, dir = q >> 10;
        int w = ng>>7, g = (ng>>5)&3, jl = ng&31;
        int row = g*256 + w*32 + jl;
        uint32_t v = 0u;
        if (kp < 153) {
          const float* s = (dir ? Wih_b : Wih_f) + (size_t)row*306 + 2*kp;
          v = pack2(s[0], s[1]);
        }
        wWihs[id] = v;
      } else if ((id -= P5) < P6) {      // sent bias sums [dir][j][g]
        int g = id & 3, j = (id>>2)&255, dir = id>>10;
        int row = g*256+j;
        wbss[id] = dir ? (bih_b[row]+bhh_b[row]) : (bih_f[row]+bhh_f[row]);
      } else { id -= P6;                 // Wo packed [kp][o]
        int o = id & 31, kp = id>>5;
        const float* s = Wo + (size_t)o*512 + 2*kp;
        wWo[id] = pack2(s[0], s[1]);
      }
    }
    return;
  }

  // ---------------- word role ----------------
  __shared__ __align__(16) uint32_t lets[11520];      // [t20][m16][36] f16x2 (72 cols, 50 real)
  __shared__ __align__(16) uint16_t hbuf[2][2176];    // [m16][136]
  const int tid = threadIdx.x;
  const int wave = tid >> 6, lane = tid & 63;
  const int l15 = lane & 15, l4 = lane >> 4;
  const int wg0 = blockIdx.x * 16;

  // self-pack B fragments from raw fp32 weights (same layout as before)
  uint4 Bh[4][4], Bx[4][2];
  #pragma unroll
  for (int g = 0; g < 4; ++g) {
    const int row = g*128 + wave*16 + l15;
    #pragma unroll
    for (int Kt = 0; Kt < 4; ++Kt) {
      const float* s = Whh_w + (size_t)row*128 + Kt*32 + l4*8;
      float4 f0 = *(const float4*)s, f1 = *(const float4*)(s + 4);
      Bh[g][Kt] = make_uint4(pack2(f0.x,f0.y), pack2(f0.z,f0.w),
                             pack2(f1.x,f1.y), pack2(f1.z,f1.w));
    }
    #pragma unroll
    for (int Kt = 0; Kt < 2; ++Kt) {
      const int k0 = Kt*32 + l4*8;
      float v[8];
      #pragma unroll
      for (int e = 0; e < 8; ++e) {
        int k = k0 + e;
        v[e] = (k < 50) ? Wih_w[(size_t)row*50 + k] : 0.f;
      }
      Bx[g][Kt] = make_uint4(pack2(v[0],v[1]), pack2(v[2],v[3]),
                             pack2(v[4],v[5]), pack2(v[6],v[7]));
    }
  }
  // bias sums for this lane's j
  float4 bs;
  {
    const int j = wave*16 + l15;
    bs.x = bih_w[0*128+j] + bhh_w[0*128+j];
    bs.y = bih_w[1*128+j] + bhh_w[1*128+j];
    bs.z = bih_w[2*128+j] + bhh_w[2*128+j];
    bs.w = bih_w[3*128+j] + bhh_w[3*128+j];
  }
  // bert: sent[wg, 128+ii] = Xw[wg, 20+ii, 0]
  for (int i = tid; i < 16*178; i += 512) {
    int m = i / 178, ii = i - m*178;
    sent[(size_t)(wg0+m)*SROW + 128 + ii] = X[(size_t)(wg0+m)*9900 + (20+ii)*50];
  }
  for (int i = tid; i < 11520; i += 512) {
    int c = i % 36, mt = i / 36; int m = mt & 15, t = mt >> 4;
    lets[i] = (c < 25) ? pack2(X[(size_t)(wg0+m)*9900 + t*50 + 2*c],
                               X[(size_t)(wg0+m)*9900 + t*50 + 2*c + 1]) : 0u;
  }
  for (int i = tid; i < 2048; i += 512) {
    int m = i >> 7, k = i & 127;
    hbuf[0][m*136 + k] = f16b(h0w[(size_t)(wg0+m)*128 + k]);
  }
  float cr[4];
  #pragma unroll
  for (int r = 0; r < 4; ++r) cr[r] = c0w[(size_t)(wg0 + l4*4 + r)*128 + wave*16 + l15];
  __syncthreads();

  uint16_t* hc = hbuf[0];
  uint16_t* hn = hbuf[1];
  const uint16_t* lp = (const uint16_t*)lets;
  #pragma unroll 1
  for (int t = 0; t < 20; ++t) {
    f32x4_t acc[4];
    acc[0] = (f32x4_t){bs.x,bs.x,bs.x,bs.x};
    acc[1] = (f32x4_t){bs.y,bs.y,bs.y,bs.y};
    acc[2] = (f32x4_t){bs.z,bs.z,bs.z,bs.z};
    acc[3] = (f32x4_t){bs.w,bs.w,bs.w,bs.w};
    #pragma unroll
    for (int Kt = 0; Kt < 2; ++Kt) {
      uint4 av = *(const uint4*)(lp + (t*16 + l15)*72 + Kt*32 + l4*8);
      half8_t a = __builtin_bit_cast(half8_t, av);
      #pragma unroll
      for (int g = 0; g < 4; ++g)
        acc[g] = __builtin_amdgcn_mfma_f32_16x16x32_f16(a, __builtin_bit_cast(half8_t, Bx[g][Kt]), acc[g], 0,0,0);
    }
    #pragma unroll
    for (int Kt = 0; Kt < 4; ++Kt) {
      uint4 av = *(const uint4*)(hc + l15*136 + Kt*32 + l4*8);
      half8_t a = __builtin_bit_cast(half8_t, av);
      #pragma unroll
      for (int g = 0; g < 4; ++g)
        acc[g] = __builtin_amdgcn_mfma_f32_16x16x32_f16(a, __builtin_bit_cast(half8_t, Bh[g][Kt]), acc[g], 0,0,0);
    }
    #pragma unroll
    for (int r = 0; r < 4; ++r) {
      float cc = sigm(acc[1][r])*cr[r] + sigm(acc[0][r])*tanhf_(acc[2][r]);
      cr[r] = cc;
      float hh = sigm(acc[3][r])*tanhf_(cc);
      hn[(l4*4+r)*136 + wave*16 + l15] = f16b(hh);
    }
    uint16_t* tp = hc; hc = hn; hn = tp;
    __syncthreads();
  }
  // word_rep = h_19 @ Wl^T + bl -> sent[:,0:128]
  uint4 Bl[4];
  #pragma unroll
  for (int Kt = 0; Kt < 4; ++Kt) {
    const float* s = Wl + (size_t)(wave*16 + l15)*128 + Kt*32 + l4*8;
    float4 f0 = *(const float4*)s, f1 = *(const float4*)(s + 4);
    Bl[Kt] = make_uint4(pack2(f0.x,f0.y), pack2(f0.z,f0.w),
                        pack2(f1.x,f1.y), pack2(f1.z,f1.w));
  }
  f32x4_t a2 = (f32x4_t){0.f,0.f,0.f,0.f};
  #pragma unroll
  for (int Kt = 0; Kt < 4; ++Kt) {
    uint4 av = *(const uint4*)(hc + l15*136 + Kt*32 + l4*8);
    a2 = __builtin_amdgcn_mfma_f32_16x16x32_f16(__builtin_bit_cast(half8_t, av),
                                                __builtin_bit_cast(half8_t, Bl[Kt]), a2, 0,0,0);
  }
  const float blv = bl[wave*16 + l15];
  #pragma unroll
  for (int r = 0; r < 4; ++r)
    sent[(size_t)(wg0 + l4*4 + r)*SROW + wave*16 + l15] = a2[r] + blv;
}

// ---- sentence xg GEMM via MFMA: 128 blocks = (dir, tt). M=32 (all b), 8 waves x N=128.
__global__ __launch_bounds__(512) void k_sxg(
    const float* __restrict__ sent, const uint32_t* __restrict__ Wihs,
    const float* __restrict__ bss, uint2* __restrict__ xgq)
{
  __shared__ __align__(16) uint16_t xs[32*ASTR];
  const int tid = threadIdx.x;
  const int wave = tid >> 6, lane = tid & 63;
  const int l15 = lane & 15, l4 = lane >> 4;
  const int dir = blockIdx.x >> 6, tt = blockIdx.x & 63;
  const int si = dir ? (63 - tt) : tt;

  for (int i = tid; i < 32*160; i += 512) {
    int kp = i % 160, b = i / 160;
    uint32_t v = 0u;
    if (kp < 153) {
      const float* s = sent + (size_t)(b*64 + si)*SROW + 2*kp;
      v = pack2(s[0], s[1]);
    }
    *(uint32_t*)(xs + b*ASTR + 2*kp) = v;
  }
  __syncthreads();

  f32x4_t acc[2][8];
  #pragma unroll
  for (int Nt = 0; Nt < 8; ++Nt) {                  // Nt = g*2 + jh
    int g = Nt >> 1, jh = Nt & 1;
    float bv = bss[(dir*256 + wave*32 + jh*16 + l15)*4 + g];
    acc[0][Nt] = (f32x4_t){bv,bv,bv,bv};
    acc[1][Nt] = (f32x4_t){bv,bv,bv,bv};
  }
  const uint32_t* Bb = Wihs + (size_t)(dir*1024 + wave*128)*160 + l15*160 + l4*4;
  #pragma unroll
  for (int Kt = 0; Kt < 10; ++Kt) {
    uint4 av0 = *(const uint4*)(xs + l15*ASTR + Kt*32 + l4*8);
    uint4 av1 = *(const uint4*)(xs + (16 + l15)*ASTR + Kt*32 + l4*8);
    half8_t a0 = __builtin_bit_cast(half8_t, av0);
    half8_t a1 = __builtin_bit_cast(half8_t, av1);
    #pragma unroll
    for (int Nt = 0; Nt < 8; ++Nt) {
      uint4 bv = *(const uint4*)(Bb + (size_t)Nt*16*160 + Kt*16);
      half8_t b = __builtin_bit_cast(half8_t, bv);
      acc[0][Nt] = __builtin_amdgcn_mfma_f32_16x16x32_f16(a0, b, acc[0][Nt], 0,0,0);
      acc[1][Nt] = __builtin_amdgcn_mfma_f32_16x16x32_f16(a1, b, acc[1][Nt], 0,0,0);
    }
  }
  #pragma unroll
  for (int Mt = 0; Mt < 2; ++Mt)
    #pragma unroll
    for (int jh = 0; jh < 2; ++jh)
      #pragma unroll
      for (int r = 0; r < 4; ++r) {
        uint2 v;
        v.x = pack2(acc[Mt][0+jh][r], acc[Mt][2+jh][r]);   // {i, f}
        v.y = pack2(acc[Mt][4+jh][r], acc[Mt][6+jh][r]);   // {g, o}
        size_t idx = ((((size_t)(dir*64 + tt)*2 + Mt)*8 + wave)*2 + jh)*256 + l15*16 + l4*4 + r;
        xgq[idx] = v;
      }
}

// ---- sentence recurrence: unchanged (best measured: 191 us)
__global__ __launch_bounds__(512, 2) void k_srec(
    const uint32_t* __restrict__ Ws, const float* __restrict__ h0f, const float* __restrict__ c0f,
    const float* __restrict__ h0b, const float* __restrict__ c0b,
    const uint2* __restrict__ xgq, uint16_t* __restrict__ outfb)
{
  extern __shared__ char smem[];               // [0,131072) B-frags, then h dbuf 2x[16][HSTR]
  uint16_t* h16a = (uint16_t*)(smem + 131072);
  uint16_t* h16b = h16a + 16*HSTR;
  const int tid = threadIdx.x;
  const int wave = tid >> 6, lane = tid & 63;
  const int dir = blockIdx.x >> 1, half = blockIdx.x & 1, m0 = half * 16;
  const int l15 = lane & 15, l4 = lane >> 4;

  uint4 Breg[8][6];
  #pragma unroll
  for (int Nt = 0; Nt < 8; ++Nt) {
    #pragma unroll
    for (int Kt = 0; Kt < 8; ++Kt) {
      int ng = wave*128 + Nt*16 + l15;
      uint4 v = *(const uint4*)(Ws + (size_t)(dir*1024 + ng)*128 + Kt*16 + l4*4);
      if (Kt < 6) Breg[Nt][Kt] = v;
      else *(uint4*)(smem + (((wave*16 + Nt*2 + (Kt-6))*64 + lane)*16)) = v;
    }
  }
  {
    const float* h0 = dir ? h0b : h0f;
    for (int i = tid; i < 16*256; i += 512) {
      int m = i >> 8, k = i & 255;
      h16a[m*HSTR + k] = f16b(h0[(size_t)(m0+m)*256 + k]);
    }
  }
  float cr[2][4];
  {
    const float* c0 = dir ? c0b : c0f;
    #pragma unroll
    for (int jh = 0; jh < 2; ++jh)
      #pragma unroll
      for (int r = 0; r < 4; ++r)
        cr[jh][r] = c0[(size_t)(m0 + l4*4 + r)*256 + wave*32 + jh*16 + l15];
  }
  __syncthreads();

  const char* xbase = (const char*)xgq + (size_t)dir*4194304 + half*32768;
  const uint32_t xlane = wave*4096 + l15*128 + l4*32;
  const int s0 = dir ? 63 : 0;
  const int sdelta = dir ? -65536 : 65536;
  const char* obase = (const char*)outfb + (size_t)s0*65536 + half*32768 + dir*16384;
  const uint32_t olane = (l4*4)*512 + wave*64 + l15*2;
  const uint32_t aoff = l15*HSTR + l4*8;

  uint16_t* hc = h16a;
  uint16_t* hn = h16b;

#define UPD1(JH, R, GI, GF, GG, GO) {                                         \
    float eo = __expf(-(GO));                                                 \
    float ef = __expf(-(GF)), ei = __expf(-(GI)), eg = __expf(-2.f*(GG));     \
    float pef = 1.f + ef, pei = 1.f + ei, peg = 1.f + eg;                     \
    float num = cr[JH][R]*pei*peg + (1.f - eg)*pef;                           \
    float cc  = num * __builtin_amdgcn_rcpf(pef*pei*peg);                     \
    cr[JH][R] = cc;                                                           \
    float ec = __expf(-2.f*cc);                                               \
    float hh = (1.f - ec) * __builtin_amdgcn_rcpf((1.f + ec)*(1.f + eo));     \
    uint16_t hb = f16b(hh);                                                   \
    hn[(l4*4+(R))*HSTR + wave*32 + (JH)*16 + l15] = hb;                       \
    *(uint16_t*)(obase + olane + (R)*512 + (JH)*32) = hb;                     \
  }

  uint4 p0 = *(const uint4*)(xbase + xlane);
  uint4 p1 = *(const uint4*)(xbase + xlane + 16);
  uint4 p2 = *(const uint4*)(xbase + xlane + 2048);
  uint4 p3 = *(const uint4*)(xbase + xlane + 2064);

  #pragma unroll 1
  for (int t = 0; t < 64; ++t) {
    f32x4_t acc[8];
    acc[0] = (f32x4_t){lo16(p0.x), lo16(p0.z), lo16(p1.x), lo16(p1.z)};
    acc[2] = (f32x4_t){hi16(p0.x), hi16(p0.z), hi16(p1.x), hi16(p1.z)};
    acc[4] = (f32x4_t){lo16(p0.y), lo16(p0.w), lo16(p1.y), lo16(p1.w)};
    acc[6] = (f32x4_t){hi16(p0.y), hi16(p0.w), hi16(p1.y), hi16(p1.w)};
    acc[1] = (f32x4_t){lo16(p2.x), lo16(p2.z), lo16(p3.x), lo16(p3.z)};
    acc[3] = (f32x4_t){hi16(p2.x), hi16(p2.z), hi16(p3.x), hi16(p3.z)};
    acc[5] = (f32x4_t){lo16(p2.y), lo16(p2.w), lo16(p3.y), lo16(p3.w)};
    acc[7] = (f32x4_t){hi16(p2.y), hi16(p2.w), hi16(p3.y), hi16(p3.w)};

    __builtin_amdgcn_s_setprio(1);
    #pragma unroll
    for (int Kt = 0; Kt < 8; ++Kt) {
      uint4 av = *(const uint4*)(hc + aoff + Kt*32);
      half8_t a = __builtin_bit_cast(half8_t, av);
      #pragma unroll
      for (int g = 0; g < 4; ++g) {
        const int Nt = g*2;
        uint4 bv;
        if (Kt < 6) bv = Breg[Nt][Kt];
        else bv = *(const uint4*)(smem + (((wave*16 + Nt*2 + (Kt-6))*64 + lane)*16));
        acc[Nt] = __builtin_amdgcn_mfma_f32_16x16x32_f16(a, __builtin_bit_cast(half8_t, bv), acc[Nt], 0,0,0);
      }
    }
    __builtin_amdgcn_s_setprio(0);

    #pragma unroll
    for (int Kt = 0; Kt < 8; ++Kt) {
      uint4 av = *(const uint4*)(hc + aoff + Kt*32);
      half8_t a = __builtin_bit_cast(half8_t, av);
      #pragma unroll
      for (int g = 0; g < 4; ++g) {
        const int Nt = g*2 + 1;
        uint4 bv;
        if (Kt < 6) bv = Breg[Nt][Kt];
        else bv = *(const uint4*)(smem + (((wave*16 + Nt*2 + (Kt-6))*64 + lane)*16));
        acc[Nt] = __builtin_amdgcn_mfma_f32_16x16x32_f16(a, __builtin_bit_cast(half8_t, bv), acc[Nt], 0,0,0);
      }
      if (Kt & 1) {
        const int r = Kt >> 1;
        UPD1(0, r, acc[0][r], acc[2][r], acc[4][r], acc[6][r]);
        __builtin_amdgcn_sched_group_barrier(0x008, 8, 0);
        __builtin_amdgcn_sched_group_barrier(0x002, 44, 0);
      }
    }

    p0 = *(const uint4*)(xbase + xlane + 65536);
    p1 = *(const uint4*)(xbase + xlane + 65536 + 16);
    p2 = *(const uint4*)(xbase + xlane + 65536 + 2048);
    p3 = *(const uint4*)(xbase + xlane + 65536 + 2064);

    #pragma unroll
    for (int r = 0; r < 4; ++r)
      UPD1(1, r, acc[1][r], acc[3][r], acc[5][r], acc[7][r]);

    { uint16_t* tp = hc; hc = hn; hn = tp; }
    xbase += 65536;
    obase += sdelta;
    asm volatile("s_waitcnt lgkmcnt(0)\ns_barrier" ::: "memory");
  }
#undef UPD1
}

// ---- tags + softmax (reads the verified outfb layout)
__global__ __launch_bounds__(256) void k_tags(
    const uint16_t* __restrict__ outfb, const uint32_t* __restrict__ Wo16,
    const float* __restrict__ bo, float* __restrict__ out)
{
  __shared__ uint32_t xr[8*256];
  const int tid = threadIdx.x;
  const int w0 = blockIdx.x * 8;
  const uint32_t* src = (const uint32_t*)outfb;
  for (int i = tid; i < 2048; i += 256) {
    int w = i >> 8, kp = i & 255;
    int widx = w0 + w;
    int s = widx & 63, q = widx >> 6;
    int half = q >> 4, m = q & 15;
    int dir = kp >> 7, wv = (kp >> 4) & 7, jh = (kp >> 3) & 1, l15h = kp & 7;
    xr[i] = src[s*16384 + half*8192 + dir*4096 + m*128 + wv*16 + jh*8 + l15h];
  }
  __syncthreads();
  const int o = tid & 31, w = tid >> 5;
  float a = bo[o];
  for (int kp = 0; kp < 256; ++kp)
    a = fdot2(Wo16[kp*32 + o], xr[w*256 + kp], a);
  float mx = a;
  #pragma unroll
  for (int off = 16; off; off >>= 1) mx = fmaxf(mx, __shfl_xor(mx, off, 32));
  float e = __expf(a - mx);
  float ssum = e;
  #pragma unroll
  for (int off = 16; off; off >>= 1) ssum += __shfl_xor(ssum, off, 32);
  out[(size_t)(w0+w)*32 + o] = e * __builtin_amdgcn_rcpf(ssum);
}

extern "C" void kernel_launch(void* const* d_in, const int* in_sizes, int n_in,
                              void* d_out, int out_size, void* d_ws, size_t ws_size,
                              hipStream_t stream) {
  const float* X     = (const float*)d_in[0];
  const float* h0w   = (const float*)d_in[1];
  const float* c0w   = (const float*)d_in[2];
  const float* h0f   = (const float*)d_in[3];
  const float* c0f   = (const float*)d_in[4];
  const float* h0b   = (const float*)d_in[5];
  const float* c0b   = (const float*)d_in[6];
  const float* Wih_w = (const float*)d_in[7];
  const float* Whh_w = (const float*)d_in[8];
  const float* bih_w = (const float*)d_in[9];
  const float* bhh_w = (const float*)d_in[10];
  const float* Wl    = (const float*)d_in[11];
  const float* bl    = (const float*)d_in[12];
  const float* Wih_f = (const float*)d_in[13];
  const float* Whh_f = (const float*)d_in[14];
  const float* bih_f = (const float*)d_in[15];
  const float* bhh_f = (const float*)d_in[16];
  const float* Wih_b = (const float*)d_in[17];
  const float* Whh_b = (const float*)d_in[18];
  const float* bih_b = (const float*)d_in[19];
  const float* bhh_b = (const float*)d_in[20];
  const float* Wo    = (const float*)d_in[21];
  const float* bo    = (const float*)d_in[22];

  char* ws = (char*)d_ws;
  uint32_t* wWs   = (uint32_t*)(ws + 0);          // 1048576 B
  uint32_t* wWihs = (uint32_t*)(ws + 1048576);    // 1310720 B
  float*    wbss  = (float*)   (ws + 2359296);    // 8192 B
  uint32_t* wWo   = (uint32_t*)(ws + 2367488);    // 32768 B
  float*    sent  = (float*)   (ws + 2400256);    // 2523136 B
  uint2*    xgq   = (uint2*)   (ws + 4923392);    // 8388608 B
  uint16_t* outfb = (uint16_t*)(ws + 13312000);   // 2097152 B -> end ~15.4 MB

  hipFuncSetAttribute((const void*)k_srec, hipFuncAttributeMaxDynamicSharedMemorySize, 148992);

  // MEASUREMENT ROUND: k_wp launched twice (idempotent). dur(total) - R10 total = dur(k_wp) + 1 gap.
  k_wp<<<512, 512, 0, stream>>>(X, h0w, c0w, Wih_w, Whh_w, bih_w, bhh_w, Wl, bl,
                                Wih_f, Whh_f, Wih_b, Whh_b,
                                bih_f, bhh_f, bih_b, bhh_b, Wo,
                                wWs, wWihs, wbss, wWo, sent);
  k_wp<<<512, 512, 0, stream>>>(X, h0w, c0w, Wih_w, Whh_w, bih_w, bhh_w, Wl, bl,
                                Wih_f, Whh_f, Wih_b, Whh_b,
                                bih_f, bhh_f, bih_b, bhh_b, Wo,
                                wWs, wWihs, wbss, wWo, sent);
  k_sxg<<<128, 512, 0, stream>>>(sent, wWihs, wbss, xgq);
  k_srec<<<4, 512, 148992, stream>>>(wWs, h0f, c0f, h0b, c0b, xgq, outfb);
  k_tags<<<256, 256, 0, stream>>>(outfb, wWo, bo, (float*)d_out);
}

// Round 12
// 274.214 us; speedup vs baseline: 1.1763x; 1.1763x over previous
//
#include <hip/hip_runtime.h>
#include <cstdint>
#include <cstddef>

#define DI static __device__ __forceinline__

using half_t  = _Float16;
using half2_t = __attribute__((ext_vector_type(2))) _Float16;
using half8_t = __attribute__((ext_vector_type(8))) _Float16;
using f32x4_t = __attribute__((ext_vector_type(4))) float;

DI uint32_t pack2(float a, float b){ half2_t h; h[0]=(half_t)a; h[1]=(half_t)b; return __builtin_bit_cast(uint32_t,h); }
DI uint16_t f16b(float a){ return __builtin_bit_cast(uint16_t,(half_t)a); }
DI float lo16(uint32_t u){ half2_t h=__builtin_bit_cast(half2_t,u); return (float)h[0]; }
DI float hi16(uint32_t u){ half2_t h=__builtin_bit_cast(half2_t,u); return (float)h[1]; }
DI float fdot2(uint32_t w, uint32_t x, float acc){
  return __builtin_amdgcn_fdot2(__builtin_bit_cast(half2_t,w), __builtin_bit_cast(half2_t,x), acc, false);
}
DI float sigm(float x){ return __builtin_amdgcn_rcpf(1.f + __expf(-x)); }
DI float tanhf_(float x){ return 1.f - 2.f*__builtin_amdgcn_rcpf(__expf(2.f*x)+1.f); }

// problem sizes: B=32 S=64 NW=2048 T=198 L=50 WLEN=20 BERT=178 Hs=128 Hm=256 Din=306 O=32
#define SROW 308   // sentences_in row stride (306 used)
#define HSTR 280   // k_srec h-row stride in halves
#define ASTR 344   // k_sxg A-row stride in halves

// prep-role job sizes (sentence weights only; word weights self-packed in word role)
#define P4 262144  // sent Whh B-frag layout [dir][ng1024][kp128], ng = w*128 + g*32 + jl
#define P5 327680  // sent Wih B-frag layout [dir][ng1024][kp160] (306 -> kp<153, rest 0)
#define P6 2048    // sent bias sum [dir][j256][g4]
#define P7 8192    // Wo f16x2 [kp256][o32]
#define PTOT (P4+P5+P6+P7)

// ---- fused kernel: blocks 0..255 = word LSTM (8 words/block, MFMA, self-packed weights);
//      blocks 256..511 = sentence-weight prep (grid-stride).
__global__ __launch_bounds__(512, 2) void k_wp(
    const float* __restrict__ X, const float* __restrict__ h0w, const float* __restrict__ c0w,
    const float* __restrict__ Wih_w, const float* __restrict__ Whh_w,
    const float* __restrict__ bih_w, const float* __restrict__ bhh_w,
    const float* __restrict__ Wl, const float* __restrict__ bl,
    const float* __restrict__ Wih_f, const float* __restrict__ Whh_f,
    const float* __restrict__ Wih_b, const float* __restrict__ Whh_b,
    const float* __restrict__ bih_f, const float* __restrict__ bhh_f,
    const float* __restrict__ bih_b, const float* __restrict__ bhh_b,
    const float* __restrict__ Wo,
    uint32_t* __restrict__ wWs, uint32_t* __restrict__ wWihs,
    float* __restrict__ wbss, uint32_t* __restrict__ wWo,
    float* __restrict__ sent)
{
  if (blockIdx.x >= 256) {
    // ---------------- prep role ----------------
    for (int i = (blockIdx.x - 256)*blockDim.x + threadIdx.x; i < PTOT;
         i += (gridDim.x - 256)*blockDim.x) {
      int id = i;
      if (id < P4) {                     // sent Whh B-frags
        int kp = id & 127, ng = (id>>7)&1023, dir = id>>17;
        int w = ng>>7, g = (ng>>5)&3, jl = ng&31;
        int row = g*256 + w*32 + jl;
        const float* s = (dir ? Whh_b : Whh_f) + (size_t)row*256 + 2*kp;
        wWs[id] = pack2(s[0], s[1]);
      } else if ((id -= P4) < P5) {      // sent Wih B-frags [dir][ng1024][kp160]
        int kp = id % 160; int q = id / 160;
        int ng = q & 1023, dir = q >> 10;
        int w = ng>>7, g = (ng>>5)&3, jl = ng&31;
        int row = g*256 + w*32 + jl;
        uint32_t v = 0u;
        if (kp < 153) {
          const float* s = (dir ? Wih_b : Wih_f) + (size_t)row*306 + 2*kp;
          v = pack2(s[0], s[1]);
        }
        wWihs[id] = v;
      } else if ((id -= P5) < P6) {      // sent bias sums [dir][j][g]
        int g = id & 3, j = (id>>2)&255, dir = id>>10;
        int row = g*256+j;
        wbss[id] = dir ? (bih_b[row]+bhh_b[row]) : (bih_f[row]+bhh_f[row]);
      } else { id -= P6;                 // Wo packed [kp][o]
        int o = id & 31, kp = id>>5;
        const float* s = Wo + (size_t)o*512 + 2*kp;
        wWo[id] = pack2(s[0], s[1]);
      }
    }
    return;
  }

  // ---------------- word role: 8 words, rows 8..15 of the M=16 tile are zero ----------------
  __shared__ __align__(16) uint32_t lets[11520];      // [t20][m16][36] f16x2 (rows 8..15 zero)
  __shared__ __align__(16) uint16_t hbuf[2][2176];    // [m16][136] (rows 8..15 zero, both bufs)
  const int tid = threadIdx.x;
  const int wave = tid >> 6, lane = tid & 63;
  const int l15 = lane & 15, l4 = lane >> 4;
  const int wg0 = blockIdx.x * 8;

  // self-pack B fragments from raw fp32 weights (same layout as verified)
  uint4 Bh[4][4], Bx[4][2];
  #pragma unroll
  for (int g = 0; g < 4; ++g) {
    const int row = g*128 + wave*16 + l15;
    #pragma unroll
    for (int Kt = 0; Kt < 4; ++Kt) {
      const float* s = Whh_w + (size_t)row*128 + Kt*32 + l4*8;
      float4 f0 = *(const float4*)s, f1 = *(const float4*)(s + 4);
      Bh[g][Kt] = make_uint4(pack2(f0.x,f0.y), pack2(f0.z,f0.w),
                             pack2(f1.x,f1.y), pack2(f1.z,f1.w));
    }
    #pragma unroll
    for (int Kt = 0; Kt < 2; ++Kt) {
      const int k0 = Kt*32 + l4*8;
      float v[8];
      #pragma unroll
      for (int e = 0; e < 8; ++e) {
        int k = k0 + e;
        v[e] = (k < 50) ? Wih_w[(size_t)row*50 + k] : 0.f;
      }
      Bx[g][Kt] = make_uint4(pack2(v[0],v[1]), pack2(v[2],v[3]),
                             pack2(v[4],v[5]), pack2(v[6],v[7]));
    }
  }
  // bias sums for this lane's j
  float4 bs;
  {
    const int j = wave*16 + l15;
    bs.x = bih_w[0*128+j] + bhh_w[0*128+j];
    bs.y = bih_w[1*128+j] + bhh_w[1*128+j];
    bs.z = bih_w[2*128+j] + bhh_w[2*128+j];
    bs.w = bih_w[3*128+j] + bhh_w[3*128+j];
  }
  // bert: sent[wg, 128+ii] = Xw[wg, 20+ii, 0]
  for (int i = tid; i < 8*178; i += 512) {
    int m = i / 178, ii = i - m*178;
    sent[(size_t)(wg0+m)*SROW + 128 + ii] = X[(size_t)(wg0+m)*9900 + (20+ii)*50];
  }
  // letters: rows m<8 real, rows 8..15 zero
  for (int i = tid; i < 11520; i += 512) {
    int c = i % 36, mt = i / 36; int m = mt & 15, t = mt >> 4;
    uint32_t v = 0u;
    if (c < 25 && m < 8) {
      const float* xp = X + (size_t)(wg0+m)*9900 + t*50 + 2*c;
      v = pack2(xp[0], xp[1]);
    }
    lets[i] = v;
  }
  // h0: rows m<8 real, rows 8..15 zero (buf0); zero rows 8..15 of buf1
  for (int i = tid; i < 2048; i += 512) {
    int m = i >> 7, k = i & 127;
    uint16_t v = 0;
    if (m < 8) v = f16b(h0w[(size_t)(wg0+m)*128 + k]);
    hbuf[0][m*136 + k] = v;
  }
  for (int i = tid; i < 1024; i += 512) {
    int m = 8 + (i >> 7), k = i & 127;
    hbuf[1][m*136 + k] = 0;
  }
  float cr[4];
  #pragma unroll
  for (int r = 0; r < 4; ++r) {
    cr[r] = 0.f;
    if (l4 < 2) cr[r] = c0w[(size_t)(wg0 + l4*4 + r)*128 + wave*16 + l15];
  }
  __syncthreads();

  uint16_t* hc = hbuf[0];
  uint16_t* hn = hbuf[1];
  const uint16_t* lp = (const uint16_t*)lets;
  #pragma unroll 1
  for (int t = 0; t < 20; ++t) {
    f32x4_t acc[4];
    acc[0] = (f32x4_t){bs.x,bs.x,bs.x,bs.x};
    acc[1] = (f32x4_t){bs.y,bs.y,bs.y,bs.y};
    acc[2] = (f32x4_t){bs.z,bs.z,bs.z,bs.z};
    acc[3] = (f32x4_t){bs.w,bs.w,bs.w,bs.w};
    #pragma unroll
    for (int Kt = 0; Kt < 2; ++Kt) {
      uint4 av = *(const uint4*)(lp + (t*16 + l15)*72 + Kt*32 + l4*8);
      half8_t a = __builtin_bit_cast(half8_t, av);
      #pragma unroll
      for (int g = 0; g < 4; ++g)
        acc[g] = __builtin_amdgcn_mfma_f32_16x16x32_f16(a, __builtin_bit_cast(half8_t, Bx[g][Kt]), acc[g], 0,0,0);
    }
    #pragma unroll
    for (int Kt = 0; Kt < 4; ++Kt) {
      uint4 av = *(const uint4*)(hc + l15*136 + Kt*32 + l4*8);
      half8_t a = __builtin_bit_cast(half8_t, av);
      #pragma unroll
      for (int g = 0; g < 4; ++g)
        acc[g] = __builtin_amdgcn_mfma_f32_16x16x32_f16(a, __builtin_bit_cast(half8_t, Bh[g][Kt]), acc[g], 0,0,0);
    }
    #pragma unroll
    for (int r = 0; r < 4; ++r) {
      float cc = sigm(acc[1][r])*cr[r] + sigm(acc[0][r])*tanhf_(acc[2][r]);
      cr[r] = cc;
      float hh = sigm(acc[3][r])*tanhf_(cc);
      if (l4 < 2) hn[(l4*4+r)*136 + wave*16 + l15] = f16b(hh);   // rows 8..15 stay zero
    }
    uint16_t* tp = hc; hc = hn; hn = tp;
    __syncthreads();
  }
  // word_rep = h_19 @ Wl^T + bl -> sent[:,0:128]
  uint4 Bl[4];
  #pragma unroll
  for (int Kt = 0; Kt < 4; ++Kt) {
    const float* s = Wl + (size_t)(wave*16 + l15)*128 + Kt*32 + l4*8;
    float4 f0 = *(const float4*)s, f1 = *(const float4*)(s + 4);
    Bl[Kt] = make_uint4(pack2(f0.x,f0.y), pack2(f0.z,f0.w),
                        pack2(f1.x,f1.y), pack2(f1.z,f1.w));
  }
  f32x4_t a2 = (f32x4_t){0.f,0.f,0.f,0.f};
  #pragma unroll
  for (int Kt = 0; Kt < 4; ++Kt) {
    uint4 av = *(const uint4*)(hc + l15*136 + Kt*32 + l4*8);
    a2 = __builtin_amdgcn_mfma_f32_16x16x32_f16(__builtin_bit_cast(half8_t, av),
                                                __builtin_bit_cast(half8_t, Bl[Kt]), a2, 0,0,0);
  }
  const float blv = bl[wave*16 + l15];
  #pragma unroll
  for (int r = 0; r < 4; ++r)
    if (l4 < 2)
      sent[(size_t)(wg0 + l4*4 + r)*SROW + wave*16 + l15] = a2[r] + blv;
}

// ---- sentence xg GEMM via MFMA: 128 blocks = (dir, tt). M=32 (all b), 8 waves x N=128.
__global__ __launch_bounds__(512) void k_sxg(
    const float* __restrict__ sent, const uint32_t* __restrict__ Wihs,
    const float* __restrict__ bss, uint2* __restrict__ xgq)
{
  __shared__ __align__(16) uint16_t xs[32*ASTR];
  const int tid = threadIdx.x;
  const int wave = tid >> 6, lane = tid & 63;
  const int l15 = lane & 15, l4 = lane >> 4;
  const int dir = blockIdx.x >> 6, tt = blockIdx.x & 63;
  const int si = dir ? (63 - tt) : tt;

  for (int i = tid; i < 32*160; i += 512) {
    int kp = i % 160, b = i / 160;
    uint32_t v = 0u;
    if (kp < 153) {
      const float* s = sent + (size_t)(b*64 + si)*SROW + 2*kp;
      v = pack2(s[0], s[1]);
    }
    *(uint32_t*)(xs + b*ASTR + 2*kp) = v;
  }
  __syncthreads();

  f32x4_t acc[2][8];
  #pragma unroll
  for (int Nt = 0; Nt < 8; ++Nt) {                  // Nt = g*2 + jh
    int g = Nt >> 1, jh = Nt & 1;
    float bv = bss[(dir*256 + wave*32 + jh*16 + l15)*4 + g];
    acc[0][Nt] = (f32x4_t){bv,bv,bv,bv};
    acc[1][Nt] = (f32x4_t){bv,bv,bv,bv};
  }
  const uint32_t* Bb = Wihs + (size_t)(dir*1024 + wave*128)*160 + l15*160 + l4*4;
  #pragma unroll
  for (int Kt = 0; Kt < 10; ++Kt) {
    uint4 av0 = *(const uint4*)(xs + l15*ASTR + Kt*32 + l4*8);
    uint4 av1 = *(const uint4*)(xs + (16 + l15)*ASTR + Kt*32 + l4*8);
    half8_t a0 = __builtin_bit_cast(half8_t, av0);
    half8_t a1 = __builtin_bit_cast(half8_t, av1);
    #pragma unroll
    for (int Nt = 0; Nt < 8; ++Nt) {
      uint4 bv = *(const uint4*)(Bb + (size_t)Nt*16*160 + Kt*16);
      half8_t b = __builtin_bit_cast(half8_t, bv);
      acc[0][Nt] = __builtin_amdgcn_mfma_f32_16x16x32_f16(a0, b, acc[0][Nt], 0,0,0);
      acc[1][Nt] = __builtin_amdgcn_mfma_f32_16x16x32_f16(a1, b, acc[1][Nt], 0,0,0);
    }
  }
  #pragma unroll
  for (int Mt = 0; Mt < 2; ++Mt)
    #pragma unroll
    for (int jh = 0; jh < 2; ++jh)
      #pragma unroll
      for (int r = 0; r < 4; ++r) {
        uint2 v;
        v.x = pack2(acc[Mt][0+jh][r], acc[Mt][2+jh][r]);   // {i, f}
        v.y = pack2(acc[Mt][4+jh][r], acc[Mt][6+jh][r]);   // {g, o}
        size_t idx = ((((size_t)(dir*64 + tt)*2 + Mt)*8 + wave)*2 + jh)*256 + l15*16 + l4*4 + r;
        xgq[idx] = v;
      }
}

// ---- sentence recurrence: unchanged (best measured: 191 us)
__global__ __launch_bounds__(512, 2) void k_srec(
    const uint32_t* __restrict__ Ws, const float* __restrict__ h0f, const float* __restrict__ c0f,
    const float* __restrict__ h0b, const float* __restrict__ c0b,
    const uint2* __restrict__ xgq, uint16_t* __restrict__ outfb)
{
  extern __shared__ char smem[];               // [0,131072) B-frags, then h dbuf 2x[16][HSTR]
  uint16_t* h16a = (uint16_t*)(smem + 131072);
  uint16_t* h16b = h16a + 16*HSTR;
  const int tid = threadIdx.x;
  const int wave = tid >> 6, lane = tid & 63;
  const int dir = blockIdx.x >> 1, half = blockIdx.x & 1, m0 = half * 16;
  const int l15 = lane & 15, l4 = lane >> 4;

  uint4 Breg[8][6];
  #pragma unroll
  for (int Nt = 0; Nt < 8; ++Nt) {
    #pragma unroll
    for (int Kt = 0; Kt < 8; ++Kt) {
      int ng = wave*128 + Nt*16 + l15;
      uint4 v = *(const uint4*)(Ws + (size_t)(dir*1024 + ng)*128 + Kt*16 + l4*4);
      if (Kt < 6) Breg[Nt][Kt] = v;
      else *(uint4*)(smem + (((wave*16 + Nt*2 + (Kt-6))*64 + lane)*16)) = v;
    }
  }
  {
    const float* h0 = dir ? h0b : h0f;
    for (int i = tid; i < 16*256; i += 512) {
      int m = i >> 8, k = i & 255;
      h16a[m*HSTR + k] = f16b(h0[(size_t)(m0+m)*256 + k]);
    }
  }
  float cr[2][4];
  {
    const float* c0 = dir ? c0b : c0f;
    #pragma unroll
    for (int jh = 0; jh < 2; ++jh)
      #pragma unroll
      for (int r = 0; r < 4; ++r)
        cr[jh][r] = c0[(size_t)(m0 + l4*4 + r)*256 + wave*32 + jh*16 + l15];
  }
  __syncthreads();

  const char* xbase = (const char*)xgq + (size_t)dir*4194304 + half*32768;
  const uint32_t xlane = wave*4096 + l15*128 + l4*32;
  const int s0 = dir ? 63 : 0;
  const int sdelta = dir ? -65536 : 65536;
  const char* obase = (const char*)outfb + (size_t)s0*65536 + half*32768 + dir*16384;
  const uint32_t olane = (l4*4)*512 + wave*64 + l15*2;
  const uint32_t aoff = l15*HSTR + l4*8;

  uint16_t* hc = h16a;
  uint16_t* hn = h16b;

#define UPD1(JH, R, GI, GF, GG, GO) {                                         \
    float eo = __expf(-(GO));                                                 \
    float ef = __expf(-(GF)), ei = __expf(-(GI)), eg = __expf(-2.f*(GG));     \
    float pef = 1.f + ef, pei = 1.f + ei, peg = 1.f + eg;                     \
    float num = cr[JH][R]*pei*peg + (1.f - eg)*pef;                           \
    float cc  = num * __builtin_amdgcn_rcpf(pef*pei*peg);                     \
    cr[JH][R] = cc;                                                           \
    float ec = __expf(-2.f*cc);                                               \
    float hh = (1.f - ec) * __builtin_amdgcn_rcpf((1.f + ec)*(1.f + eo));     \
    uint16_t hb = f16b(hh);                                                   \
    hn[(l4*4+(R))*HSTR + wave*32 + (JH)*16 + l15] = hb;                       \
    *(uint16_t*)(obase + olane + (R)*512 + (JH)*32) = hb;                     \
  }

  uint4 p0 = *(const uint4*)(xbase + xlane);
  uint4 p1 = *(const uint4*)(xbase + xlane + 16);
  uint4 p2 = *(const uint4*)(xbase + xlane + 2048);
  uint4 p3 = *(const uint4*)(xbase + xlane + 2064);

  #pragma unroll 1
  for (int t = 0; t < 64; ++t) {
    f32x4_t acc[8];
    acc[0] = (f32x4_t){lo16(p0.x), lo16(p0.z), lo16(p1.x), lo16(p1.z)};
    acc[2] = (f32x4_t){hi16(p0.x), hi16(p0.z), hi16(p1.x), hi16(p1.z)};
    acc[4] = (f32x4_t){lo16(p0.y), lo16(p0.w), lo16(p1.y), lo16(p1.w)};
    acc[6] = (f32x4_t){hi16(p0.y), hi16(p0.w), hi16(p1.y), hi16(p1.w)};
    acc[1] = (f32x4_t){lo16(p2.x), lo16(p2.z), lo16(p3.x), lo16(p3.z)};
    acc[3] = (f32x4_t){hi16(p2.x), hi16(p2.z), hi16(p3.x), hi16(p3.z)};
    acc[5] = (f32x4_t){lo16(p2.y), lo16(p2.w), lo16(p3.y), lo16(p3.w)};
    acc[7] = (f32x4_t){hi16(p2.y), hi16(p2.w), hi16(p3.y), hi16(p3.w)};

    __builtin_amdgcn_s_setprio(1);
    #pragma unroll
    for (int Kt = 0; Kt < 8; ++Kt) {
      uint4 av = *(const uint4*)(hc + aoff + Kt*32);
      half8_t a = __builtin_bit_cast(half8_t, av);
      #pragma unroll
      for (int g = 0; g < 4; ++g) {
        const int Nt = g*2;
        uint4 bv;
        if (Kt < 6) bv = Breg[Nt][Kt];
        else bv = *(const uint4*)(smem + (((wave*16 + Nt*2 + (Kt-6))*64 + lane)*16));
        acc[Nt] = __builtin_amdgcn_mfma_f32_16x16x32_f16(a, __builtin_bit_cast(half8_t, bv), acc[Nt], 0,0,0);
      }
    }
    __builtin_amdgcn_s_setprio(0);

    #pragma unroll
    for (int Kt = 0; Kt < 8; ++Kt) {
      uint4 av = *(const uint4*)(hc + aoff + Kt*32);
      half8_t a = __builtin_bit_cast(half8_t, av);
      #pragma unroll
      for (int g = 0; g < 4; ++g) {
        const int Nt = g*2 + 1;
        uint4 bv;
        if (Kt < 6) bv = Breg[Nt][Kt];
        else bv = *(const uint4*)(smem + (((wave*16 + Nt*2 + (Kt-6))*64 + lane)*16));
        acc[Nt] = __builtin_amdgcn_mfma_f32_16x16x32_f16(a, __builtin_bit_cast(half8_t, bv), acc[Nt], 0,0,0);
      }
      if (Kt & 1) {
        const int r = Kt >> 1;
        UPD1(0, r, acc[0][r], acc[2][r], acc[4][r], acc[6][r]);
        __builtin_amdgcn_sched_group_barrier(0x008, 8, 0);
        __builtin_amdgcn_sched_group_barrier(0x002, 44, 0);
      }
    }

    p0 = *(const uint4*)(xbase + xlane + 65536);
    p1 = *(const uint4*)(xbase + xlane + 65536 + 16);
    p2 = *(const uint4*)(xbase + xlane + 65536 + 2048);
    p3 = *(const uint4*)(xbase + xlane + 65536 + 2064);

    #pragma unroll
    for (int r = 0; r < 4; ++r)
      UPD1(1, r, acc[1][r], acc[3][r], acc[5][r], acc[7][r]);

    { uint16_t* tp = hc; hc = hn; hn = tp; }
    xbase += 65536;
    obase += sdelta;
    asm volatile("s_waitcnt lgkmcnt(0)\ns_barrier" ::: "memory");
  }
#undef UPD1
}

// ---- tags + softmax (reads the verified outfb layout)
__global__ __launch_bounds__(256) void k_tags(
    const uint16_t* __restrict__ outfb, const uint32_t* __restrict__ Wo16,
    const float* __restrict__ bo, float* __restrict__ out)
{
  __shared__ uint32_t xr[8*256];
  const int tid = threadIdx.x;
  const int w0 = blockIdx.x * 8;
  const uint32_t* src = (const uint32_t*)outfb;
  for (int i = tid; i < 2048; i += 256) {
    int w = i >> 8, kp = i & 255;
    int widx = w0 + w;
    int s = widx & 63, q = widx >> 6;
    int half = q >> 4, m = q & 15;
    int dir = kp >> 7, wv = (kp >> 4) & 7, jh = (kp >> 3) & 1, l15h = kp & 7;
    xr[i] = src[s*16384 + half*8192 + dir*4096 + m*128 + wv*16 + jh*8 + l15h];
  }
  __syncthreads();
  const int o = tid & 31, w = tid >> 5;
  float a = bo[o];
  for (int kp = 0; kp < 256; ++kp)
    a = fdot2(Wo16[kp*32 + o], xr[w*256 + kp], a);
  float mx = a;
  #pragma unroll
  for (int off = 16; off; off >>= 1) mx = fmaxf(mx, __shfl_xor(mx, off, 32));
  float e = __expf(a - mx);
  float ssum = e;
  #pragma unroll
  for (int off = 16; off; off >>= 1) ssum += __shfl_xor(ssum, off, 32);
  out[(size_t)(w0+w)*32 + o] = e * __builtin_amdgcn_rcpf(ssum);
}

extern "C" void kernel_launch(void* const* d_in, const int* in_sizes, int n_in,
                              void* d_out, int out_size, void* d_ws, size_t ws_size,
                              hipStream_t stream) {
  const float* X     = (const float*)d_in[0];
  const float* h0w   = (const float*)d_in[1];
  const float* c0w   = (const float*)d_in[2];
  const float* h0f   = (const float*)d_in[3];
  const float* c0f   = (const float*)d_in[4];
  const float* h0b   = (const float*)d_in[5];
  const float* c0b   = (const float*)d_in[6];
  const float* Wih_w = (const float*)d_in[7];
  const float* Whh_w = (const float*)d_in[8];
  const float* bih_w = (const float*)d_in[9];
  const float* bhh_w = (const float*)d_in[10];
  const float* Wl    = (const float*)d_in[11];
  const float* bl    = (const float*)d_in[12];
  const float* Wih_f = (const float*)d_in[13];
  const float* Whh_f = (const float*)d_in[14];
  const float* bih_f = (const float*)d_in[15];
  const float* bhh_f = (const float*)d_in[16];
  const float* Wih_b = (const float*)d_in[17];
  const float* Whh_b = (const float*)d_in[18];
  const float* bih_b = (const float*)d_in[19];
  const float* bhh_b = (const float*)d_in[20];
  const float* Wo    = (const float*)d_in[21];
  const float* bo    = (const float*)d_in[22];

  char* ws = (char*)d_ws;
  uint32_t* wWs   = (uint32_t*)(ws + 0);          // 1048576 B
  uint32_t* wWihs = (uint32_t*)(ws + 1048576);    // 1310720 B
  float*    wbss  = (float*)   (ws + 2359296);    // 8192 B
  uint32_t* wWo   = (uint32_t*)(ws + 2367488);    // 32768 B
  float*    sent  = (float*)   (ws + 2400256);    // 2523136 B
  uint2*    xgq   = (uint2*)   (ws + 4923392);    // 8388608 B
  uint16_t* outfb = (uint16_t*)(ws + 13312000);   // 2097152 B -> end ~15.4 MB

  hipFuncSetAttribute((const void*)k_srec, hipFuncAttributeMaxDynamicSharedMemorySize, 148992);

  k_wp<<<512, 512, 0, stream>>>(X, h0w, c0w, Wih_w, Whh_w, bih_w, bhh_w, Wl, bl,
                                Wih_f, Whh_f, Wih_b, Whh_b,
                                bih_f, bhh_f, bih_b, bhh_b, Wo,
                                wWs, wWihs, wbss, wWo, sent);
  k_sxg<<<128, 512, 0, stream>>>(sent, wWihs, wbss, xgq);
  k_srec<<<4, 512, 148992, stream>>>(wWs, h0f, c0f, h0b, c0b, xgq, outfb);
  k_tags<<<256, 256, 0, stream>>>(outfb, wWo, bo, (float*)d_out);
}